// Round 8
// baseline (126.311 us; speedup 1.0000x reference)
//
#include <hip/hip_runtime.h>
#include <math.h>

// Problem dims (fixed by setup_inputs)
#define HW   16384
#define BS   16
#define C    256
#define NQ   100
#define NQP  112          // padded nq (7 x 16)
#define Hh   128
#define Ww   128

// output layout offsets (floats)
#define SIM_OFF   3200                 // after proposal_for_loss [16,100,2]
#define PROPS_OFF (3200 + 26214400)    // after similarity [16,100,16384]

#define BM 256           // hw per block
#define BK 32            // k per step (== MFMA K)
#define NBLK (HW / BM)   // 64 partials per row

typedef _Float16 half8 __attribute__((ext_vector_type(8)));
typedef float f32x4 __attribute__((ext_vector_type(4)));

__device__ __forceinline__ void gll16(const void* gp, void* lp) {
    __builtin_amdgcn_global_load_lds((const __attribute__((address_space(1))) void*)gp,
                                     (__attribute__((address_space(3))) void*)lp, 16, 0, 0);
}

__device__ __forceinline__ void split8(const float4 a, const float4 b, half8& hi, half8& lo) {
    float f[8] = {a.x, a.y, a.z, a.w, b.x, b.y, b.z, b.w};
    _Float16 h[8], l[8];
    #pragma unroll
    for (int i = 0; i < 8; ++i) {
        h[i] = (_Float16)f[i];
        l[i] = (_Float16)(f[i] - (float)h[i]);
    }
    hi = *(half8*)h;
    lo = *(half8*)l;
}

// ---------------- S pre-split kernel ----------------
// S [nq, bs, c] fp32 -> Shi/Slo [bs][112][256] fp16 (rows >= NQ zero)
__global__ __launch_bounds__(256) void split_S_kernel(const float* __restrict__ S,
                                                      _Float16* __restrict__ shi,
                                                      _Float16* __restrict__ slo)
{
    int idx4 = blockIdx.x * 256 + threadIdx.x;
    int idx = idx4 * 4;
    if (idx >= BS * NQP * C) return;
    int b = idx / (NQP * C);
    int rem = idx - b * (NQP * C);
    int n = rem / C;
    int k = rem - n * C;
    float4 v = make_float4(0.f, 0.f, 0.f, 0.f);
    if (n < NQ) v = *(const float4*)(S + ((size_t)n * BS + b) * C + k);
    _Float16 h[4], l[4];
    float f[4] = {v.x, v.y, v.z, v.w};
    #pragma unroll
    for (int i = 0; i < 4; ++i) {
        h[i] = (_Float16)f[i];
        l[i] = (_Float16)(f[i] - (float)h[i]);
    }
    *(uint2*)(shi + idx) = *(uint2*)h;
    *(uint2*)(slo + idx) = *(uint2*)l;
}

// ---------------- split-fp16 MFMA GEMM (R3 structure) + fused row stats ----------------
// sim[b][n][k] = sum_c S[n][b][c] * Q[k][b][c]
// Partials layout is BLOCK-CONTIGUOUS: p[(b*NBLK + blk)*NQ + n] -- single
// writer per cache line (no cross-XCD false sharing).
template<bool USE_WS>
__global__ __launch_bounds__(256, 2) void gemm_kernel(const float* __restrict__ Q,
                                                      const float* __restrict__ S,
                                                      const _Float16* __restrict__ ShiG,
                                                      const _Float16* __restrict__ SloG,
                                                      float* __restrict__ out,
                                                      float* __restrict__ pm,
                                                      float* __restrict__ pz,
                                                      float* __restrict__ pwx,
                                                      float* __restrict__ pwy,
                                                      int* __restrict__ pidx)
{
    // Qf: 256 rows x 32 f32 (128 B row). chunk c (16B) stored at slot c ^ (row&7).
    __shared__ __align__(16) float    Qf[BM * BK];         // 32 KB
    // SHI/SLO: 112 rows x 32 f16 (64 B row). chunk c (16B) at slot c ^ ((row>>1)&3).
    __shared__ __align__(16) _Float16 SHI[NQP * BK];       // 7 KB
    __shared__ __align__(16) _Float16 SLO[NQP * BK];       // 7 KB
    __shared__ float Lm[NQP][4], Lz[NQP][4], Lwx[NQP][4];
    __shared__ int   Li[NQP][4];

    const int b    = blockIdx.y;
    const int hw0  = blockIdx.x * BM;
    const int t    = threadIdx.x;
    const int wid  = t >> 6;
    const int lane = t & 63;
    const int lr   = lane & 15;    // A-row / B-col within fragment
    const int lg   = lane >> 4;    // k-group (0..3)

    f32x4 acc[7][4];
    #pragma unroll
    for (int n = 0; n < 7; ++n)
        #pragma unroll
        for (int m = 0; m < 4; ++m)
            acc[n][m] = (f32x4)(0.f);

    // staging lane decomposition
    const int q_r8 = lane >> 3;                       // row within 8-row group
    const int q_gc = (lane & 7) ^ q_r8;               // pre-swizzled global chunk (f32 x4)
    const int s_r  = lane >> 2;                       // row within 16-row group
    const int s_gc = (lane & 3) ^ ((lane >> 3) & 3);  // pre-swizzled global chunk (f16 x8)

    for (int k0 = 0; k0 < C; k0 += BK) {
        // ---- stage Q tile via global_load_lds (8 insts/thread, 8 rows each) ----
        #pragma unroll
        for (int p = 0; p < 8; ++p) {
            int rt = wid * 64 + p * 8;
            const float* g = Q + ((size_t)(hw0 + rt + q_r8) * BS + b) * C + k0 + q_gc * 4;
            gll16(g, &Qf[rt * BK]);
        }
        // ---- stage S hi/lo tiles (pre-split) ----
        if (USE_WS) {
            for (int i = wid; i < 14; i += 4) {
                int r0 = (i % 7) * 16;
                _Float16* dst = (i < 7) ? &SHI[r0 * BK] : &SLO[r0 * BK];
                const _Float16* src = (i < 7) ? ShiG : SloG;
                const _Float16* g = src + ((size_t)b * NQP + r0 + s_r) * C + k0 + s_gc * 8;
                gll16(g, dst);
            }
        }
        __syncthreads();

        // ---- B fragments (Q): read swizzled f32 chunks, split hi/lo ----
        half8 bhi[4], blo[4];
        #pragma unroll
        for (int m = 0; m < 4; ++m) {
            int row = wid * 64 + 16 * m + lr;
            int r7 = row & 7;
            float4 qa = *(const float4*)&Qf[row * BK + (((2 * lg + 0) ^ r7) << 2)];
            float4 qb = *(const float4*)&Qf[row * BK + (((2 * lg + 1) ^ r7) << 2)];
            split8(qa, qb, bhi[m], blo[m]);
        }

        // ---- A fragments + 3-pass MFMA ----
        #pragma unroll
        for (int n = 0; n < 7; ++n) {
            int row = 16 * n + lr;
            half8 ahi, alo;
            if (USE_WS) {
                int slot = lg ^ ((row >> 1) & 3);
                ahi = *(const half8*)&SHI[row * BK + slot * 8];
                alo = *(const half8*)&SLO[row * BK + slot * 8];
            } else {
                if (row < NQ) {
                    const float* g = S + ((size_t)row * BS + b) * C + k0 + 8 * lg;
                    float4 sa = *(const float4*)g;
                    float4 sb = *(const float4*)(g + 4);
                    split8(sa, sb, ahi, alo);
                } else {
                    ahi = (half8)(_Float16)0.f;
                    alo = (half8)(_Float16)0.f;
                }
            }
            #pragma unroll
            for (int m = 0; m < 4; ++m) {
                acc[n][m] = __builtin_amdgcn_mfma_f32_16x16x32_f16(ahi, bhi[m], acc[n][m], 0, 0, 0);
                acc[n][m] = __builtin_amdgcn_mfma_f32_16x16x32_f16(ahi, blo[m], acc[n][m], 0, 0, 0);
                acc[n][m] = __builtin_amdgcn_mfma_f32_16x16x32_f16(alo, bhi[m], acc[n][m], 0, 0, 0);
            }
        }
        __syncthreads();
    }

    // ---- epilogue: sim store + per-block row stats ----
    // C/D layout: col = lane&15 (within frag), row = 4*(lane>>4)+j
    float* simb = out + SIM_OFF;
    #pragma unroll
    for (int n = 0; n < 7; ++n) {
        #pragma unroll
        for (int j = 0; j < 4; ++j) {
            int row = 16 * n + 4 * lg + j;
            float v0 = acc[n][0][j], v1 = acc[n][1][j], v2 = acc[n][2][j], v3 = acc[n][3][j];
            int col0 = wid * 64 + lr;                 // 0..255 within block
            if (row < NQ) {
                size_t base = ((size_t)(b * NQ + row)) * HW + hw0 + col0;
                simb[base]      = v0;
                simb[base + 16] = v1;
                simb[base + 32] = v2;
                simb[base + 48] = v3;
            }
            if (USE_WS) {
                // max over m (ascending, strict > -> lowest col wins ties)
                float vm = v0; int ci = col0;
                if (v1 > vm) { vm = v1; ci = col0 + 16; }
                if (v2 > vm) { vm = v2; ci = col0 + 32; }
                if (v3 > vm) { vm = v3; ci = col0 + 48; }
                #pragma unroll
                for (int off = 1; off < 16; off <<= 1) {
                    float ov = __shfl_xor(vm, off);
                    int   oc = __shfl_xor(ci, off);
                    if (ov > vm || (ov == vm && oc < ci)) { vm = ov; ci = oc; }
                }
                // x-coordinate within the 128-wide grid row: (global col) & 127
                float e0 = __expf(v0 - vm), e1 = __expf(v1 - vm);
                float e2 = __expf(v2 - vm), e3 = __expf(v3 - vm);
                float zt  = (e0 + e1) + (e2 + e3);
                float wxt = e0 * ((float)((col0)      & 127) + 0.5f)
                          + e1 * ((float)((col0 + 16) & 127) + 0.5f)
                          + e2 * ((float)((col0 + 32) & 127) + 0.5f)
                          + e3 * ((float)((col0 + 48) & 127) + 0.5f);
                #pragma unroll
                for (int off = 1; off < 16; off <<= 1) {
                    zt  += __shfl_xor(zt, off);
                    wxt += __shfl_xor(wxt, off);
                }
                if (lr == 0) { Lm[row][wid] = vm; Li[row][wid] = ci; Lz[row][wid] = zt; Lwx[row][wid] = wxt; }
            }
        }
    }
    if (USE_WS) {
        __syncthreads();
        if (t < NQ) {
            int row = t;
            float M = Lm[row][0]; int gi = Li[row][0];
            #pragma unroll
            for (int w = 1; w < 4; ++w) {
                float ov = Lm[row][w]; int oc = Li[row][w];
                if (ov > M || (ov == M && oc < gi)) { M = ov; gi = oc; }
            }
            float Zp = 0.f, WXp = 0.f, WYp = 0.f;
            #pragma unroll
            for (int w = 0; w < 4; ++w) {
                float s  = __expf(Lm[row][w] - M);
                float cy = (float)((hw0 + w * 64) >> 7) + 0.5f;   // y-row of this wid chunk
                Zp  += Lz[row][w] * s;
                WXp += Lwx[row][w] * s;
                WYp += Lz[row][w] * s * cy;
            }
            // block-contiguous partials: single writer per line
            size_t pbase = ((size_t)b * NBLK + blockIdx.x) * NQ + row;
            pm[pbase] = M; pz[pbase] = Zp; pwx[pbase] = WXp; pwy[pbase] = WYp;
            pidx[pbase] = hw0 + gi;
        }
    }
}

// ---------------- finalize: combine 64 partials per row ----------------
__global__ __launch_bounds__(256) void finalize_kernel(const float* __restrict__ sim,
                                                       const float* __restrict__ pm,
                                                       const float* __restrict__ pz,
                                                       const float* __restrict__ pwx,
                                                       const float* __restrict__ pwy,
                                                       const int* __restrict__ pidx,
                                                       float* __restrict__ out)
{
    const int rglob = blockIdx.x * 4 + (threadIdx.x >> 6);  // 0..1599 = b*NQ + n
    const int lane  = threadIdx.x & 63;                     // = partial block id
    const int b     = rglob / NQ;
    const int n     = rglob - b * NQ;
    const size_t base = ((size_t)b * NBLK + lane) * NQ + n;

    float m  = pm[base];
    float z  = pz[base];
    float wx = pwx[base];
    float wy = pwy[base];
    int   gi = pidx[base];

    float v = m; int vi = gi;
    #pragma unroll
    for (int off = 1; off < 64; off <<= 1) {
        float ov = __shfl_xor(v, off);
        int   oi = __shfl_xor(vi, off);
        if (ov > v || (ov == v && oi < vi)) { v = ov; vi = oi; }
    }
    float s  = __expf(m - v);
    float Z  = z * s;
    float WX = wx * s;
    float WY = wy * s;
    #pragma unroll
    for (int off = 1; off < 64; off <<= 1) {
        Z  += __shfl_xor(Z, off);
        WX += __shfl_xor(WX, off);
        WY += __shfl_xor(WY, off);
    }
    if (lane == 0) {
        out[(size_t)rglob * 2 + 0] = (WX / Z) * (1.f / 128.f);
        out[(size_t)rglob * 2 + 1] = (WY / Z) * (1.f / 128.f);
        const float* srow = sim + (size_t)rglob * HW;
        int pr = vi >> 7, pc = vi & 127;
        float ls = 0.f, lx = 0.f, ly = 0.f;
        #pragma unroll
        for (int dr = -1; dr <= 1; ++dr) {
            #pragma unroll
            for (int dc = -1; dc <= 1; ++dc) {
                int r = pr + dr, c = pc + dc;
                if (r >= 0 && r < Ww && c >= 0 && c < Hh) {
                    int k = r * Hh + c;
                    float e = __expf(srow[k] - v);
                    ls += e;
                    lx += e * ((float)(k & 127) + 0.5f);
                    ly += e * ((float)(k >> 7) + 0.5f);
                }
            }
        }
        float denom = ls + 1e-10f * Z;
        out[PROPS_OFF + (size_t)rglob * 2 + 0] = (lx / denom) * (1.f / 128.f);
        out[PROPS_OFF + (size_t)rglob * 2 + 1] = (ly / denom) * (1.f / 128.f);
    }
}

// ---------------- fallback row-reduction kernel (no-ws path) ----------------
__global__ __launch_bounds__(256) void reduce_kernel(const float* __restrict__ sim,
                                                     float* __restrict__ out)
{
    __shared__ float rowbuf[HW];
    __shared__ float s_pm[4];
    __shared__ int   s_pi[4];
    __shared__ float s_red[4][3];
    __shared__ float s_gmax;
    __shared__ int   s_gidx;

    const int row = blockIdx.x;
    const int t   = threadIdx.x;
    const int wid  = t >> 6;
    const int lane = t & 63;
    const float4* src4 = (const float4*)(sim + (size_t)row * HW);

    float vmax = -3.4e38f;
    int   vidx = 0;
    #pragma unroll
    for (int p = 0; p < 16; ++p) {
        int i4 = p * 256 + t;
        float4 v = src4[i4];
        *(float4*)&rowbuf[i4 * 4] = v;
        int base = i4 * 4;
        if (v.x > vmax) { vmax = v.x; vidx = base; }
        if (v.y > vmax) { vmax = v.y; vidx = base + 1; }
        if (v.z > vmax) { vmax = v.z; vidx = base + 2; }
        if (v.w > vmax) { vmax = v.w; vidx = base + 3; }
    }
    #pragma unroll
    for (int off = 32; off > 0; off >>= 1) {
        float ov = __shfl_down(vmax, off);
        int   oi = __shfl_down(vidx, off);
        if (ov > vmax || (ov == vmax && oi < vidx)) { vmax = ov; vidx = oi; }
    }
    if (lane == 0) { s_pm[wid] = vmax; s_pi[wid] = vidx; }
    __syncthreads();
    if (t == 0) {
        float gm = s_pm[0]; int gi = s_pi[0];
        #pragma unroll
        for (int wv = 1; wv < 4; ++wv) {
            float ov = s_pm[wv]; int oi = s_pi[wv];
            if (ov > gm || (ov == gm && oi < gi)) { gm = ov; gi = oi; }
        }
        s_gmax = gm; s_gidx = gi;
    }
    __syncthreads();
    const float gmax = s_gmax;

    float z = 0.f, wx = 0.f, wy = 0.f;
    #pragma unroll
    for (int p = 0; p < 16; ++p) {
        int i4 = p * 256 + t;
        float4 v = *(const float4*)&rowbuf[i4 * 4];
        int i = i4 * 4;
        float e0 = __expf(v.x - gmax), e1 = __expf(v.y - gmax);
        float e2 = __expf(v.z - gmax), e3 = __expf(v.w - gmax);
        z += (e0 + e1) + (e2 + e3);
        float cy = (float)(i >> 7) + 0.5f;
        float cx0 = (float)(i & (Ww - 1)) + 0.5f;
        wx += e0 * cx0 + e1 * (cx0 + 1.f) + e2 * (cx0 + 2.f) + e3 * (cx0 + 3.f);
        wy += (e0 + e1 + e2 + e3) * cy;
    }
    #pragma unroll
    for (int off = 32; off > 0; off >>= 1) {
        z  += __shfl_down(z, off);
        wx += __shfl_down(wx, off);
        wy += __shfl_down(wy, off);
    }
    if (lane == 0) { s_red[wid][0] = z; s_red[wid][1] = wx; s_red[wid][2] = wy; }
    __syncthreads();

    if (t == 0) {
        float Z = 0.f, WX = 0.f, WY = 0.f;
        #pragma unroll
        for (int wv = 0; wv < 4; ++wv) { Z += s_red[wv][0]; WX += s_red[wv][1]; WY += s_red[wv][2]; }

        out[(size_t)row * 2 + 0] = (WX / Z) * (1.0f / (float)Ww);
        out[(size_t)row * 2 + 1] = (WY / Z) * (1.0f / (float)Hh);

        int p  = s_gidx;
        int pr = p / Hh;
        int pc = p % Hh;
        float lsum = 0.f, lwx = 0.f, lwy = 0.f;
        #pragma unroll
        for (int di = -1; di <= 1; ++di) {
            #pragma unroll
            for (int dj = -1; dj <= 1; ++dj) {
                int r = pr + di, c = pc + dj;
                if (r >= 0 && r < Ww && c >= 0 && c < Hh) {
                    int k = r * Hh + c;
                    float e = __expf(rowbuf[k] - gmax);
                    lsum += e;
                    lwx  += e * ((float)(k & (Ww - 1)) + 0.5f);
                    lwy  += e * ((float)(k >> 7) + 0.5f);
                }
            }
        }
        float denom = lsum + 1e-10f * Z;
        out[PROPS_OFF + (size_t)row * 2 + 0] = (lwx / denom) * (1.0f / (float)Ww);
        out[PROPS_OFF + (size_t)row * 2 + 1] = (lwy / denom) * (1.0f / (float)Hh);
    }
}

extern "C" void kernel_launch(void* const* d_in, const int* in_sizes, int n_in,
                              void* d_out, int out_size, void* d_ws, size_t ws_size,
                              hipStream_t stream) {
    const float* Q = (const float*)d_in[0];   // [hw, bs, c]
    const float* S = (const float*)d_in[1];   // [nq, bs, c]
    float* out = (float*)d_out;

    const size_t splitElems = (size_t)BS * NQP * C;            // 458752 halves per array
    const size_t splitBytes = splitElems * 2 * sizeof(_Float16);
    const size_t nPart = (size_t)BS * NQ * NBLK;               // 102400
    const size_t pOff  = (splitBytes + 255) & ~(size_t)255;
    const size_t wsNeeded = pOff + nPart * 5 * sizeof(float);

    if (ws_size >= wsNeeded) {
        _Float16* shi = (_Float16*)d_ws;
        _Float16* slo = shi + splitElems;
        float* pm  = (float*)((char*)d_ws + pOff);
        float* pz  = pm + nPart;
        float* pwx = pz + nPart;
        float* pwy = pwx + nPart;
        int*   pidx = (int*)(pwy + nPart);
        split_S_kernel<<<dim3((unsigned)((splitElems / 4 + 255) / 256)), 256, 0, stream>>>(S, shi, slo);
        gemm_kernel<true><<<dim3(HW / BM, BS), 256, 0, stream>>>(Q, S, shi, slo, out,
                                                                 pm, pz, pwx, pwy, pidx);
        finalize_kernel<<<dim3(BS * NQ / 4), 256, 0, stream>>>(out + SIM_OFF, pm, pz, pwx, pwy, pidx, out);
    } else {
        gemm_kernel<false><<<dim3(HW / BM, BS), 256, 0, stream>>>(Q, S, nullptr, nullptr, out,
                                                                  nullptr, nullptr, nullptr, nullptr, nullptr);
        reduce_kernel<<<dim3(BS * NQ), 256, 0, stream>>>(out + SIM_OFF, out);
    }
}

// Round 9
// 110.276 us; speedup vs baseline: 1.1454x; 1.1454x over previous
//
#include <hip/hip_runtime.h>
#include <math.h>

// Problem dims (fixed by setup_inputs)
#define HW   16384
#define BS   16
#define C    256
#define NQ   100
#define NQP  112          // padded nq (7 x 16)
#define Hh   128
#define Ww   128

// output layout offsets (floats)
#define SIM_OFF   3200                 // after proposal_for_loss [16,100,2]
#define PROPS_OFF (3200 + 26214400)    // after similarity [16,100,16384]

#define BM 256           // hw per block
#define BK 32            // k per step (== MFMA K)
#define NBLK (HW / BM)   // 64 partials per row

typedef _Float16 half8 __attribute__((ext_vector_type(8)));
typedef float f32x4 __attribute__((ext_vector_type(4)));

__device__ __forceinline__ void gll16(const void* gp, void* lp) {
    __builtin_amdgcn_global_load_lds((const __attribute__((address_space(1))) void*)gp,
                                     (__attribute__((address_space(3))) void*)lp, 16, 0, 0);
}

__device__ __forceinline__ void split8(const float4 a, const float4 b, half8& hi, half8& lo) {
    float f[8] = {a.x, a.y, a.z, a.w, b.x, b.y, b.z, b.w};
    _Float16 h[8], l[8];
    #pragma unroll
    for (int i = 0; i < 8; ++i) {
        h[i] = (_Float16)f[i];
        l[i] = (_Float16)(f[i] - (float)h[i]);
    }
    hi = *(half8*)h;
    lo = *(half8*)l;
}

// ---------------- S pre-split kernel ----------------
// S [nq, bs, c] fp32 -> Shi/Slo [bs][112][256] fp16 (rows >= NQ zero)
__global__ __launch_bounds__(256) void split_S_kernel(const float* __restrict__ S,
                                                      _Float16* __restrict__ shi,
                                                      _Float16* __restrict__ slo)
{
    int idx4 = blockIdx.x * 256 + threadIdx.x;
    int idx = idx4 * 4;
    if (idx >= BS * NQP * C) return;
    int b = idx / (NQP * C);
    int rem = idx - b * (NQP * C);
    int n = rem / C;
    int k = rem - n * C;
    float4 v = make_float4(0.f, 0.f, 0.f, 0.f);
    if (n < NQ) v = *(const float4*)(S + ((size_t)n * BS + b) * C + k);
    _Float16 h[4], l[4];
    float f[4] = {v.x, v.y, v.z, v.w};
    #pragma unroll
    for (int i = 0; i < 4; ++i) {
        h[i] = (_Float16)f[i];
        l[i] = (_Float16)(f[i] - (float)h[i]);
    }
    *(uint2*)(shi + idx) = *(uint2*)h;
    *(uint2*)(slo + idx) = *(uint2*)l;
}

// ---------------- split-fp16 MFMA GEMM + fused row stats (swapped operands) ----------------
// sim[b][n][k] = sum_c S[n][b][c] * Q[k][b][c]
// A = Q (hw), B = S (nq): D col (lane&15) = nq, so each thread holds 16 hw
// values per nq row IN REGISTERS -> row stats are VALU + a 2-step ladder.
template<bool USE_WS>
__global__ __launch_bounds__(256, 2) void gemm_kernel(const float* __restrict__ Q,
                                                      const float* __restrict__ S,
                                                      const _Float16* __restrict__ ShiG,
                                                      const _Float16* __restrict__ SloG,
                                                      float* __restrict__ out,
                                                      float* __restrict__ pm,
                                                      float* __restrict__ pz,
                                                      float* __restrict__ pwx,
                                                      float* __restrict__ pwy,
                                                      int* __restrict__ pidx)
{
    // Qf: 256 rows x 32 f32 (128 B row). chunk c (16B) stored at slot c ^ (row&7).
    __shared__ __align__(16) float    Qf[BM * BK];         // 32 KB
    // SHI/SLO: 112 rows x 32 f16 (64 B row). chunk c (16B) at slot c ^ ((row>>1)&3).
    __shared__ __align__(16) _Float16 SHI[NQP * BK];       // 7 KB
    __shared__ __align__(16) _Float16 SLO[NQP * BK];       // 7 KB
    // per-(nq,wid) wave partial tuples {m, idx, z, wx}
    __shared__ __align__(16) float Ws[NQP][4][4];          // 7 KB

    const int b    = blockIdx.y;
    const int hw0  = blockIdx.x * BM;
    const int t    = threadIdx.x;
    const int wid  = t >> 6;
    const int lane = t & 63;
    const int lr   = lane & 15;    // A-row / B-col within fragment
    const int lg   = lane >> 4;    // k-group (0..3)

    // acc[am][bn]: rows hw = wid*64 + 16*am + 4*lg + j, col nq = 16*bn + lr
    f32x4 acc[4][7];
    #pragma unroll
    for (int am = 0; am < 4; ++am)
        #pragma unroll
        for (int bn = 0; bn < 7; ++bn)
            acc[am][bn] = (f32x4)(0.f);

    // staging lane decomposition
    const int q_r8 = lane >> 3;                       // row within 8-row group
    const int q_gc = (lane & 7) ^ q_r8;               // pre-swizzled global chunk (f32 x4)
    const int s_r  = lane >> 2;                       // row within 16-row group
    const int s_gc = (lane & 3) ^ ((lane >> 3) & 3);  // pre-swizzled global chunk (f16 x8)

    for (int k0 = 0; k0 < C; k0 += BK) {
        // ---- stage Q tile via global_load_lds (8 insts/thread, 8 rows each) ----
        #pragma unroll
        for (int p = 0; p < 8; ++p) {
            int rt = wid * 64 + p * 8;
            const float* g = Q + ((size_t)(hw0 + rt + q_r8) * BS + b) * C + k0 + q_gc * 4;
            gll16(g, &Qf[rt * BK]);
        }
        // ---- stage S hi/lo tiles (pre-split) ----
        if (USE_WS) {
            for (int i = wid; i < 14; i += 4) {
                int r0 = (i % 7) * 16;
                _Float16* dst = (i < 7) ? &SHI[r0 * BK] : &SLO[r0 * BK];
                const _Float16* src = (i < 7) ? ShiG : SloG;
                const _Float16* g = src + ((size_t)b * NQP + r0 + s_r) * C + k0 + s_gc * 8;
                gll16(g, dst);
            }
        }
        __syncthreads();

        // ---- A fragments (Q): split all 4 hw-frags ----
        half8 qhi[4], qlo[4];
        #pragma unroll
        for (int am = 0; am < 4; ++am) {
            int row = wid * 64 + 16 * am + lr;
            int r7 = row & 7;
            float4 qa = *(const float4*)&Qf[row * BK + (((2 * lg + 0) ^ r7) << 2)];
            float4 qb = *(const float4*)&Qf[row * BK + (((2 * lg + 1) ^ r7) << 2)];
            split8(qa, qb, qhi[am], qlo[am]);
        }

        // ---- B fragments (S) + 3-pass MFMA ----
        #pragma unroll
        for (int bn = 0; bn < 7; ++bn) {
            int row = 16 * bn + lr;
            half8 shi, slo;
            if (USE_WS) {
                int slot = lg ^ ((row >> 1) & 3);
                shi = *(const half8*)&SHI[row * BK + slot * 8];
                slo = *(const half8*)&SLO[row * BK + slot * 8];
            } else {
                if (row < NQ) {
                    const float* g = S + ((size_t)row * BS + b) * C + k0 + 8 * lg;
                    float4 sa = *(const float4*)g;
                    float4 sb = *(const float4*)(g + 4);
                    split8(sa, sb, shi, slo);
                } else {
                    shi = (half8)(_Float16)0.f;
                    slo = (half8)(_Float16)0.f;
                }
            }
            #pragma unroll
            for (int am = 0; am < 4; ++am) {
                acc[am][bn] = __builtin_amdgcn_mfma_f32_16x16x32_f16(qhi[am], shi, acc[am][bn], 0, 0, 0);
                acc[am][bn] = __builtin_amdgcn_mfma_f32_16x16x32_f16(qhi[am], slo, acc[am][bn], 0, 0, 0);
                acc[am][bn] = __builtin_amdgcn_mfma_f32_16x16x32_f16(qlo[am], shi, acc[am][bn], 0, 0, 0);
            }
        }
        __syncthreads();
    }

    // ---- epilogue: sim store (dwordx4) + per-row stats (lane-local) ----
    float* simb = out + SIM_OFF;
    const int hwl0 = wid * 64 + 4 * lg;            // hw-local base for j=0, am=0
    #pragma unroll
    for (int bn = 0; bn < 7; ++bn) {
        int nq = 16 * bn + lr;
        if (nq < NQ) {
            size_t rbase = ((size_t)(b * NQ + nq)) * HW + hw0 + hwl0;
            #pragma unroll
            for (int am = 0; am < 4; ++am)
                *(float4*)&simb[rbase + 16 * am] =
                    make_float4(acc[am][bn][0], acc[am][bn][1], acc[am][bn][2], acc[am][bn][3]);
        }
        if (USE_WS) {
            // per-thread max/argmax over the 16 register values (ascending cols,
            // strict > -> lowest col wins ties)
            float vm = acc[0][bn][0];
            int   ci = hw0 + hwl0;
            #pragma unroll
            for (int am = 0; am < 4; ++am)
                #pragma unroll
                for (int j = 0; j < 4; ++j) {
                    float v = acc[am][bn][j];
                    if (v > vm) { vm = v; ci = hw0 + hwl0 + 16 * am + j; }
                }
            float z = 0.f, wx = 0.f;
            #pragma unroll
            for (int am = 0; am < 4; ++am)
                #pragma unroll
                for (int j = 0; j < 4; ++j) {
                    float e = __expf(acc[am][bn][j] - vm);
                    z += e;
                    wx += e * ((float)((hwl0 + 16 * am + j) & 127) + 0.5f);
                }
            // 2-step ladder over the 4 lg-lanes holding this nq (xor 16, 32)
            #pragma unroll
            for (int off = 16; off < 64; off <<= 1) {
                float om = __shfl_xor(vm, off);
                int   oc = __shfl_xor(ci, off);
                float oz = __shfl_xor(z, off);
                float ox = __shfl_xor(wx, off);
                bool take = (om > vm) || (om == vm && oc < ci);
                float mn = take ? om : vm;
                float ss = __expf(vm - mn);
                float so = __expf(om - mn);
                z  = z * ss + oz * so;
                wx = wx * ss + ox * so;
                vm = mn;
                ci = take ? oc : ci;
            }
            if (lg == 0) {
                Ws[nq][wid][0] = vm;
                Ws[nq][wid][1] = __int_as_float(ci);
                Ws[nq][wid][2] = z;
                Ws[nq][wid][3] = wx;
            }
        }
    }
    if (USE_WS) {
        __syncthreads();
        if (t < NQ) {
            int nq = t;
            float M = -3.4e38f; int gi = 0;
            float mw[4], zw[4], xw[4]; int cw[4];
            #pragma unroll
            for (int w = 0; w < 4; ++w) {
                f32x4 tu = *(const f32x4*)&Ws[nq][w][0];
                mw[w] = tu[0]; cw[w] = __float_as_int(tu[1]); zw[w] = tu[2]; xw[w] = tu[3];
                if (mw[w] > M || (mw[w] == M && cw[w] < gi)) { M = mw[w]; gi = cw[w]; }
            }
            float ybase = (float)(hw0 >> 7) + 0.5f;
            float Zp = 0.f, WXp = 0.f, WYp = 0.f;
            #pragma unroll
            for (int w = 0; w < 4; ++w) {
                float s = __expf(mw[w] - M);
                Zp  += zw[w] * s;
                WXp += xw[w] * s;
                WYp += zw[w] * s * (ybase + (float)(w >> 1));   // y uniform per wid
            }
            size_t pbase = ((size_t)b * NBLK + blockIdx.x) * NQ + nq;
            pm[pbase] = M; pz[pbase] = Zp; pwx[pbase] = WXp; pwy[pbase] = WYp;
            pidx[pbase] = gi;
        }
    }
}

// ---------------- finalize: combine 64 partials per row ----------------
__global__ __launch_bounds__(256) void finalize_kernel(const float* __restrict__ sim,
                                                       const float* __restrict__ pm,
                                                       const float* __restrict__ pz,
                                                       const float* __restrict__ pwx,
                                                       const float* __restrict__ pwy,
                                                       const int* __restrict__ pidx,
                                                       float* __restrict__ out)
{
    const int rglob = blockIdx.x * 4 + (threadIdx.x >> 6);  // 0..1599 = b*NQ + n
    const int lane  = threadIdx.x & 63;                     // = partial block id
    const int b     = rglob / NQ;
    const int n     = rglob - b * NQ;
    const size_t base = ((size_t)b * NBLK + lane) * NQ + n;

    float m  = pm[base];
    float z  = pz[base];
    float wx = pwx[base];
    float wy = pwy[base];
    int   gi = pidx[base];

    float v = m; int vi = gi;
    #pragma unroll
    for (int off = 1; off < 64; off <<= 1) {
        float ov = __shfl_xor(v, off);
        int   oi = __shfl_xor(vi, off);
        if (ov > v || (ov == v && oi < vi)) { v = ov; vi = oi; }
    }
    float s  = __expf(m - v);
    float Z  = z * s;
    float WX = wx * s;
    float WY = wy * s;
    #pragma unroll
    for (int off = 1; off < 64; off <<= 1) {
        Z  += __shfl_xor(Z, off);
        WX += __shfl_xor(WX, off);
        WY += __shfl_xor(WY, off);
    }
    if (lane == 0) {
        out[(size_t)rglob * 2 + 0] = (WX / Z) * (1.f / 128.f);
        out[(size_t)rglob * 2 + 1] = (WY / Z) * (1.f / 128.f);
        const float* srow = sim + (size_t)rglob * HW;
        int pr = vi >> 7, pc = vi & 127;
        float ls = 0.f, lx = 0.f, ly = 0.f;
        #pragma unroll
        for (int dr = -1; dr <= 1; ++dr) {
            #pragma unroll
            for (int dc = -1; dc <= 1; ++dc) {
                int r = pr + dr, c = pc + dc;
                if (r >= 0 && r < Ww && c >= 0 && c < Hh) {
                    int k = r * Hh + c;
                    float e = __expf(srow[k] - v);
                    ls += e;
                    lx += e * ((float)(k & 127) + 0.5f);
                    ly += e * ((float)(k >> 7) + 0.5f);
                }
            }
        }
        float denom = ls + 1e-10f * Z;
        out[PROPS_OFF + (size_t)rglob * 2 + 0] = (lx / denom) * (1.f / 128.f);
        out[PROPS_OFF + (size_t)rglob * 2 + 1] = (ly / denom) * (1.f / 128.f);
    }
}

// ---------------- fallback row-reduction kernel (no-ws path) ----------------
__global__ __launch_bounds__(256) void reduce_kernel(const float* __restrict__ sim,
                                                     float* __restrict__ out)
{
    __shared__ float rowbuf[HW];
    __shared__ float s_pm[4];
    __shared__ int   s_pi[4];
    __shared__ float s_red[4][3];
    __shared__ float s_gmax;
    __shared__ int   s_gidx;

    const int row = blockIdx.x;
    const int t   = threadIdx.x;
    const int wid  = t >> 6;
    const int lane = t & 63;
    const float4* src4 = (const float4*)(sim + (size_t)row * HW);

    float vmax = -3.4e38f;
    int   vidx = 0;
    #pragma unroll
    for (int p = 0; p < 16; ++p) {
        int i4 = p * 256 + t;
        float4 v = src4[i4];
        *(float4*)&rowbuf[i4 * 4] = v;
        int base = i4 * 4;
        if (v.x > vmax) { vmax = v.x; vidx = base; }
        if (v.y > vmax) { vmax = v.y; vidx = base + 1; }
        if (v.z > vmax) { vmax = v.z; vidx = base + 2; }
        if (v.w > vmax) { vmax = v.w; vidx = base + 3; }
    }
    #pragma unroll
    for (int off = 32; off > 0; off >>= 1) {
        float ov = __shfl_down(vmax, off);
        int   oi = __shfl_down(vidx, off);
        if (ov > vmax || (ov == vmax && oi < vidx)) { vmax = ov; vidx = oi; }
    }
    if (lane == 0) { s_pm[wid] = vmax; s_pi[wid] = vidx; }
    __syncthreads();
    if (t == 0) {
        float gm = s_pm[0]; int gi = s_pi[0];
        #pragma unroll
        for (int wv = 1; wv < 4; ++wv) {
            float ov = s_pm[wv]; int oi = s_pi[wv];
            if (ov > gm || (ov == gm && oi < gi)) { gm = ov; gi = oi; }
        }
        s_gmax = gm; s_gidx = gi;
    }
    __syncthreads();
    const float gmax = s_gmax;

    float z = 0.f, wx = 0.f, wy = 0.f;
    #pragma unroll
    for (int p = 0; p < 16; ++p) {
        int i4 = p * 256 + t;
        float4 v = *(const float4*)&rowbuf[i4 * 4];
        int i = i4 * 4;
        float e0 = __expf(v.x - gmax), e1 = __expf(v.y - gmax);
        float e2 = __expf(v.z - gmax), e3 = __expf(v.w - gmax);
        z += (e0 + e1) + (e2 + e3);
        float cy = (float)(i >> 7) + 0.5f;
        float cx0 = (float)(i & (Ww - 1)) + 0.5f;
        wx += e0 * cx0 + e1 * (cx0 + 1.f) + e2 * (cx0 + 2.f) + e3 * (cx0 + 3.f);
        wy += (e0 + e1 + e2 + e3) * cy;
    }
    #pragma unroll
    for (int off = 32; off > 0; off >>= 1) {
        z  += __shfl_down(z, off);
        wx += __shfl_down(wx, off);
        wy += __shfl_down(wy, off);
    }
    if (lane == 0) { s_red[wid][0] = z; s_red[wid][1] = wx; s_red[wid][2] = wy; }
    __syncthreads();

    if (t == 0) {
        float Z = 0.f, WX = 0.f, WY = 0.f;
        #pragma unroll
        for (int wv = 0; wv < 4; ++wv) { Z += s_red[wv][0]; WX += s_red[wv][1]; WY += s_red[wv][2]; }

        out[(size_t)row * 2 + 0] = (WX / Z) * (1.0f / (float)Ww);
        out[(size_t)row * 2 + 1] = (WY / Z) * (1.0f / (float)Hh);

        int p  = s_gidx;
        int pr = p / Hh;
        int pc = p % Hh;
        float lsum = 0.f, lwx = 0.f, lwy = 0.f;
        #pragma unroll
        for (int di = -1; di <= 1; ++di) {
            #pragma unroll
            for (int dj = -1; dj <= 1; ++dj) {
                int r = pr + di, c = pc + dj;
                if (r >= 0 && r < Ww && c >= 0 && c < Hh) {
                    int k = r * Hh + c;
                    float e = __expf(rowbuf[k] - gmax);
                    lsum += e;
                    lwx  += e * ((float)(k & (Ww - 1)) + 0.5f);
                    lwy  += e * ((float)(k >> 7) + 0.5f);
                }
            }
        }
        float denom = lsum + 1e-10f * Z;
        out[PROPS_OFF + (size_t)row * 2 + 0] = (lwx / denom) * (1.0f / (float)Ww);
        out[PROPS_OFF + (size_t)row * 2 + 1] = (lwy / denom) * (1.0f / (float)Hh);
    }
}

extern "C" void kernel_launch(void* const* d_in, const int* in_sizes, int n_in,
                              void* d_out, int out_size, void* d_ws, size_t ws_size,
                              hipStream_t stream) {
    const float* Q = (const float*)d_in[0];   // [hw, bs, c]
    const float* S = (const float*)d_in[1];   // [nq, bs, c]
    float* out = (float*)d_out;

    const size_t splitElems = (size_t)BS * NQP * C;            // 458752 halves per array
    const size_t splitBytes = splitElems * 2 * sizeof(_Float16);
    const size_t nPart = (size_t)BS * NQ * NBLK;               // 102400
    const size_t pOff  = (splitBytes + 255) & ~(size_t)255;
    const size_t wsNeeded = pOff + nPart * 5 * sizeof(float);

    if (ws_size >= wsNeeded) {
        _Float16* shi = (_Float16*)d_ws;
        _Float16* slo = shi + splitElems;
        float* pm  = (float*)((char*)d_ws + pOff);
        float* pz  = pm + nPart;
        float* pwx = pz + nPart;
        float* pwy = pwx + nPart;
        int*   pidx = (int*)(pwy + nPart);
        split_S_kernel<<<dim3((unsigned)((splitElems / 4 + 255) / 256)), 256, 0, stream>>>(S, shi, slo);
        gemm_kernel<true><<<dim3(HW / BM, BS), 256, 0, stream>>>(Q, S, shi, slo, out,
                                                                 pm, pz, pwx, pwy, pidx);
        finalize_kernel<<<dim3(BS * NQ / 4), 256, 0, stream>>>(out + SIM_OFF, pm, pz, pwx, pwy, pidx, out);
    } else {
        gemm_kernel<false><<<dim3(HW / BM, BS), 256, 0, stream>>>(Q, S, nullptr, nullptr, out,
                                                                  nullptr, nullptr, nullptr, nullptr, nullptr);
        reduce_kernel<<<dim3(BS * NQ), 256, 0, stream>>>(out + SIM_OFF, out);
    }
}